// Round 1
// baseline (147.951 us; speedup 1.0000x reference)
//
#include <hip/hip_runtime.h>
#include <math.h>

#define BB 8192
#define DD 768
#define EE 16
#define PP 4

__global__ __launch_bounds__(256) void moe_fused(
    const float* __restrict__ h,      // [B, D, E]
    const float* __restrict__ x,      // [B, D]
    const float* __restrict__ W,      // [E, D]
    const float* __restrict__ bias,   // [E]
    const float* __restrict__ Pw,     // [P, E, E]
    float* __restrict__ y,            // [B, D]
    float* __restrict__ avgs)         // [32]: soft[16], hard[16]
{
    __shared__ float xs[DD];
    __shared__ float lg[EE];
    __shared__ float sp[EE];
    __shared__ int   topidx[2];
    __shared__ float topsm[2];

    const int t = threadIdx.x;
    const int b = blockIdx.x;

    // ---- Stage 1: x row -> LDS (float4) ----
    const float4* x4 = (const float4*)(x + (size_t)b * DD);
    if (t < DD / 4) {
        ((float4*)xs)[t] = x4[t];   // 192 float4 = 768 floats
    }
    __syncthreads();

    // ---- Stage 2: logits[e] = dot(x[b], W[e]) + bias[e] ----
    const int e   = t >> 4;     // 16 threads per expert
    const int sub = t & 15;
    const float* wrow = W + e * DD;
    float part = 0.f;
    #pragma unroll 8
    for (int k = sub; k < DD; k += 16)
        part = fmaf(xs[k], wrow[k], part);
    // reduce within aligned 16-lane groups (wave = 64)
    #pragma unroll
    for (int off = 8; off >= 1; off >>= 1)
        part += __shfl_xor(part, off, 64);
    if (sub == 0) lg[e] = part + bias[e];
    __syncthreads();

    // ---- Stage 3: top-2 + masked softmax (reference: scattered==0 -> -inf) ----
    if (t == 0) {
        float v0 = -INFINITY, v1 = -INFINITY;
        int   i0 = 0, i1 = 0;
        #pragma unroll
        for (int j = 0; j < EE; ++j) {
            float v = lg[j];
            if (v > v0)      { v1 = v0; i1 = i0; v0 = v; i0 = j; }
            else if (v > v1) { v1 = v;  i1 = j; }
        }
        float z0 = (v0 == 0.f) ? -INFINITY : v0;
        float z1 = (v1 == 0.f) ? -INFINITY : v1;
        float m  = fmaxf(z0, z1);
        float e0 = __expf(z0 - m) == __expf(z0 - m) ? expf(z0 - m) : 0.f; // keep exact expf
        float e1 = expf(z1 - m);
        e0 = expf(z0 - m);
        float inv = 1.f / (e0 + e1);
        topidx[0] = i0; topidx[1] = i1;
        topsm[0] = e0 * inv; topsm[1] = e1 * inv;
    }
    __syncthreads();

    // ---- Stage 4: s_perm row + average atomics (threads 0..15) ----
    if (t < EE) {
        const int   i0 = topidx[0], i1 = topidx[1];
        const float sm0 = topsm[0], sm1 = topsm[1];
        float pm0 = 0.f, pm1 = 0.f;
        #pragma unroll
        for (int p = 0; p < PP; ++p) {
            pm0 += Pw[p * EE * EE + i0 * EE + t];
            pm1 += Pw[p * EE * EE + i1 * EE + t];
        }
        pm0 *= 0.25f; pm1 *= 0.25f;
        const float s = sm0 * pm0 + sm1 * pm1;
        sp[t] = s;
        const float invB = 1.0f / BB;
        atomicAdd(&avgs[t], s * invB);
        atomicAdd(&avgs[EE + t], (s >= 1e-5f) ? invB : 0.f);
    }
    __syncthreads();

    // ---- Stage 5: y[b,d] = sum_e h[b,d,e] * sp[e] (h stream, float4) ----
    const float4 s0 = ((const float4*)sp)[0];
    const float4 s1 = ((const float4*)sp)[1];
    const float4 s2 = ((const float4*)sp)[2];
    const float4 s3 = ((const float4*)sp)[3];
    const float* hb = h + (size_t)b * DD * EE;
    float* yb = y + (size_t)b * DD;
    #pragma unroll
    for (int it = 0; it < 3; ++it) {
        const int d = t + it * 256;
        const float4* h4 = (const float4*)(hb + (size_t)d * EE);
        float4 a  = h4[0];
        float4 bq = h4[1];
        float4 c  = h4[2];
        float4 dq = h4[3];
        float acc = a.x * s0.x + a.y * s0.y + a.z * s0.z + a.w * s0.w
                  + bq.x * s1.x + bq.y * s1.y + bq.z * s1.z + bq.w * s1.w
                  + c.x * s2.x + c.y * s2.y + c.z * s2.z + c.w * s2.w
                  + dq.x * s3.x + dq.y * s3.y + dq.z * s3.z + dq.w * s3.w;
        yb[d] = acc;
    }
}

extern "C" void kernel_launch(void* const* d_in, const int* in_sizes, int n_in,
                              void* d_out, int out_size, void* d_ws, size_t ws_size,
                              hipStream_t stream) {
    const float* h    = (const float*)d_in[0];   // [8192, 768, 16]
    const float* x    = (const float*)d_in[1];   // [8192, 768]
    const float* W    = (const float*)d_in[2];   // [16, 768]
    const float* bias = (const float*)d_in[3];   // [16]
    const float* Pw   = (const float*)d_in[4];   // [4, 16, 16]

    float* y    = (float*)d_out;                 // [8192, 768]
    float* avgs = y + (size_t)BB * DD;           // soft[16] ++ hard[16]

    // zero the accumulator tail (atomics add into it every call)
    hipMemsetAsync(avgs, 0, 2 * EE * sizeof(float), stream);

    moe_fused<<<BB, 256, 0, stream>>>(h, x, W, bias, Pw, y, avgs);
}